// Round 12
// baseline (739.056 us; speedup 1.0000x reference)
//
#include <hip/hip_runtime.h>
#include <hip/hip_fp16.h>

// B=256,S=256,T=32,H=512,E=128,V=1000,A=8,NT=80.
// Decoder is dead code (softmax shift-invariance over S) -> outputs tiled pa/pt.
// 256 serial LSTM steps: 16 batch-groups x (16 rows, 16 wgs); Wh in registers,
// x-part precomputed (P = embed@Wi.T + b, fp32 gather).
// History: R13 write-once NaN-XOR exchange via enc_out, serial poll + LDS
// stage = 733.5us (lstm 563, 2.2us/step). R20 chain-split NULL => sync
// ~1.8us/step dominates. R22 2-deep poll in C: NaN FAIL -- in-flight load-dest
// regs exposed as C values; regalloc copies between issue and waitcnt read
// undefined data. LESSON: pipelined polls must be ONE asm block with fixed
// clobbered regs (R4's stable flag-poll pattern).
// R23 (this): R13 byte-exact except the poll is a single-asm 2-deep pipelined
// poll: issue A+B rounds into v[40:55]/v[56:71]; loop {vmcnt(4); check A
// (min-chain + cmp + cbranch_vccz); reissue A; vmcnt(4); check B; reissue B;
// s_sleep 1}. Accept path drains vmcnt(0) BEFORE block exit (no stale regs,
// compiler vmcnt accounting trivially safe -- same invariant R13 relied on),
// then v_mov accepted round to "=&v" outputs. Sampling quantum (RT+64) ->
// ~(RT+64)/2; traffic ~= R13 (one sleep per 2 checks). Wave-uniform branches.

#define Sv 256
#define Tv 32
#define Hv 512
#define KT 16          // k-tiles of 32 over K=512 (h only; x-part via P gather)
#define LDSA 520       // padded row stride in halfs (1040B = 65*16, b128-aligned)
#define GM 16          // batch rows per group

#define ENC_KEY 0x7FFF7FFFu   // per-half 0x7FFF = fp16 NaN: unreachable by gate math

typedef _Float16 half8 __attribute__((ext_vector_type(8)));
typedef __attribute__((ext_vector_type(4))) float f32x4;
typedef __attribute__((ext_vector_type(4))) unsigned uint4v;

__device__ __forceinline__ float sigm(float x) { return 1.0f / (1.0f + __expf(-x)); }
__device__ __forceinline__ float tanh_fast(float x) {
  x = fminf(15.f, fmaxf(-15.f, x));
  float e = __expf(2.f * x);
  return (e - 1.f) / (e + 1.f);
}

// ---- P[v][n] = sum_k embed[v][k]*Wi[n][k] + be[n], fp32. 250 blocks x 4 tokens.
__global__ __launch_bounds__(256)
void build_P(const float* __restrict__ embed, const float* __restrict__ Wi,
             const float* __restrict__ be, float* __restrict__ P)
{
  __shared__ float ev[4][128];
  const int tid = threadIdx.x;
  const int v0  = blockIdx.x * 4;
#pragma unroll
  for (int i = 0; i < 2; ++i) {
    int e = tid + i * 256;
    ev[e >> 7][e & 127] = embed[(v0 + (e >> 7)) * 128 + (e & 127)];
  }
  __syncthreads();
#pragma unroll 1
  for (int cc = 0; cc < 8; ++cc) {
    int n = cc * 256 + tid;
    float b = be[n];
    float a0 = b, a1 = b, a2 = b, a3 = b;
    const f32x4* w = (const f32x4*)(Wi + n * 128);
#pragma unroll
    for (int k4 = 0; k4 < 32; ++k4) {
      f32x4 wv = w[k4];
#pragma unroll
      for (int j = 0; j < 4; ++j) {
        float wj = wv[j];
        int k = k4 * 4 + j;
        a0 += wj * ev[0][k]; a1 += wj * ev[1][k];
        a2 += wj * ev[2][k]; a3 += wj * ev[3][k];
      }
    }
    P[(size_t)(v0 + 0) * 2048 + n] = a0;
    P[(size_t)(v0 + 1) * 2048 + n] = a1;
    P[(size_t)(v0 + 2) * 2048 + n] = a2;
    P[(size_t)(v0 + 3) * 2048 + n] = a3;
  }
}

// enc_out doubles as the h-exchange buffer: write-once per (row, step), each
// dword stored XOR ENC_KEY via agent-scope atomic (never 0). Consumers poll
// their own b128 stage loads until all dwords nonzero, decode, write LDS.
__global__ __launch_bounds__(256, 1)
void lstm_enc(const int* __restrict__ enc_in, const float* __restrict__ P,
              const float* __restrict__ Wh, __half* __restrict__ enc_out)
{
  __shared__ __attribute__((aligned(16))) _Float16 Ah[GM][LDSA];
  __shared__ float zbuf[4][GM][37];

  const int tid  = threadIdx.x;
  const int wg   = blockIdx.x;
  const int g    = wg & 15;   // group (members share wg%8 -> same XCD heuristically; perf only)
  const int cb   = wg >> 4;   // column block: owns z-cols [q*512 + cb*32, +32) per gate q
  const int wave = tid >> 6;  // wave == gate q (0=i,1=f,2=g,3=o)
  const int lane = tid & 63;
  const int m16  = lane & 15;
  const int qd   = lane >> 4;

  // ---- Wh fragments in registers (fp16): lane holds W'[n][k] for
  // n = wave*512 + cb*32 + nt*16 + m16, k = kt*32 + qd*8 + j (j=0..7).
  half8 wf[KT][2];
#pragma unroll
  for (int kt = 0; kt < KT; ++kt) {
#pragma unroll
    for (int nt = 0; nt < 2; ++nt) {
      int n  = wave * 512 + cb * 32 + nt * 16 + m16;
      int k0 = kt * 32 + qd * 8;
      const float* src = Wh + (size_t)n * Hv + k0;
      f32x4 f0 = *(const f32x4*)(src);
      f32x4 f1 = *(const f32x4*)(src + 4);
      half8 w;
      w[0] = (_Float16)f0[0]; w[1] = (_Float16)f0[1];
      w[2] = (_Float16)f0[2]; w[3] = (_Float16)f0[3];
      w[4] = (_Float16)f1[0]; w[5] = (_Float16)f1[1];
      w[6] = (_Float16)f1[2]; w[7] = (_Float16)f1[3];
      wf[kt][nt] = w;
    }
  }

  // gates-phase mapping: thread owns (row gr, cols gj, gj+1); c-state in regs
  const int gr = tid >> 4;
  const int gj = (tid & 15) * 2;
  float c0 = 0.f, c1 = 0.f;

  // ---- P prefetch for s=0 (acc-layout rows r0..r0+3, cols ncol, ncol+16)
  const int r0   = qd * 4;
  const int ncol = wave * 512 + cb * 32 + m16;
  float px0[4], px1[4];
#pragma unroll
  for (int rr = 0; rr < 4; ++rr) {
    int tk  = enc_in[(g * GM + r0 + rr) * Sv + 0];
    px0[rr] = P[(size_t)tk * 2048 + ncol];
    px1[rr] = P[(size_t)tk * 2048 + ncol + 16];
  }

  // ---- stage geometry: thread loads 4 chunks, chunk j = row j*4+rw,
  // halfs [colh, colh+8) of the previous step's enc_out row.
  const int rw   = tid >> 6;
  const int colh = (tid & 63) * 8;
  const size_t rowstride = (size_t)Sv * Hv;  // halfs per batch row
  size_t rb[4];
#pragma unroll
  for (int j = 0; j < 4; ++j)
    rb[j] = (size_t)(g * GM + j * 4 + rw) * rowstride + colh;

  const uint4v K4 = {ENC_KEY, ENC_KEY, ENC_KEY, ENC_KEY};

#pragma unroll 1
  for (int s = 0; s < Sv; ++s) {
    if (s > 0) {
      // ---- single-asm 2-deep pipelined poll of h(s-1). Rounds A=v[40:55],
      // B=v[56:71]; temps v72-74. Exits only after vmcnt(0) drain; outputs
      // moved from fixed regs AFTER the drain (no in-flight regs escape).
      const __half* sp = enc_out + (size_t)(s - 1) * Hv;
      const void* p0 = sp + rb[0];
      const void* p1 = sp + rb[1];
      const void* p2 = sp + rb[2];
      const void* p3 = sp + rb[3];
      unsigned q0, q1, q2, q3, q4, q5, q6, q7, q8, q9, q10, q11, q12, q13, q14, q15;
      asm volatile(
        "global_load_dwordx4 v[40:43], %[P0], off sc0 sc1\n\t"
        "global_load_dwordx4 v[44:47], %[P1], off sc0 sc1\n\t"
        "global_load_dwordx4 v[48:51], %[P2], off sc0 sc1\n\t"
        "global_load_dwordx4 v[52:55], %[P3], off sc0 sc1\n\t"
        "global_load_dwordx4 v[56:59], %[P0], off sc0 sc1\n\t"
        "global_load_dwordx4 v[60:63], %[P1], off sc0 sc1\n\t"
        "global_load_dwordx4 v[64:67], %[P2], off sc0 sc1\n\t"
        "global_load_dwordx4 v[68:71], %[P3], off sc0 sc1\n\t"
        "1:\n\t"
        "s_waitcnt vmcnt(4)\n\t"           // round A landed (B still in flight)
        "v_min_u32 v72, v40, v41\n\t"
        "v_min_u32 v72, v72, v42\n\t"
        "v_min_u32 v72, v72, v43\n\t"
        "v_min_u32 v72, v72, v44\n\t"
        "v_min_u32 v72, v72, v45\n\t"
        "v_min_u32 v72, v72, v46\n\t"
        "v_min_u32 v72, v72, v47\n\t"
        "v_min_u32 v72, v72, v48\n\t"
        "v_min_u32 v72, v72, v49\n\t"
        "v_min_u32 v72, v72, v50\n\t"
        "v_min_u32 v72, v72, v51\n\t"
        "v_min_u32 v72, v72, v52\n\t"
        "v_min_u32 v72, v72, v53\n\t"
        "v_min_u32 v72, v72, v54\n\t"
        "v_min_u32 v72, v72, v55\n\t"
        "v_cmp_eq_u32 vcc, 0, v72\n\t"     // fail-lane mask
        "s_cbranch_vccz 3f\n\t"            // no lane failed -> accept A
        "global_load_dwordx4 v[40:43], %[P0], off sc0 sc1\n\t"
        "global_load_dwordx4 v[44:47], %[P1], off sc0 sc1\n\t"
        "global_load_dwordx4 v[48:51], %[P2], off sc0 sc1\n\t"
        "global_load_dwordx4 v[52:55], %[P3], off sc0 sc1\n\t"
        "s_waitcnt vmcnt(4)\n\t"           // round B landed (A' in flight)
        "v_min_u32 v72, v56, v57\n\t"
        "v_min_u32 v72, v72, v58\n\t"
        "v_min_u32 v72, v72, v59\n\t"
        "v_min_u32 v72, v72, v60\n\t"
        "v_min_u32 v72, v72, v61\n\t"
        "v_min_u32 v72, v72, v62\n\t"
        "v_min_u32 v72, v72, v63\n\t"
        "v_min_u32 v72, v72, v64\n\t"
        "v_min_u32 v72, v72, v65\n\t"
        "v_min_u32 v72, v72, v66\n\t"
        "v_min_u32 v72, v72, v67\n\t"
        "v_min_u32 v72, v72, v68\n\t"
        "v_min_u32 v72, v72, v69\n\t"
        "v_min_u32 v72, v72, v70\n\t"
        "v_min_u32 v72, v72, v71\n\t"
        "v_cmp_eq_u32 vcc, 0, v72\n\t"
        "s_cbranch_vccz 4f\n\t"            // accept B
        "global_load_dwordx4 v[56:59], %[P0], off sc0 sc1\n\t"
        "global_load_dwordx4 v[60:63], %[P1], off sc0 sc1\n\t"
        "global_load_dwordx4 v[64:67], %[P2], off sc0 sc1\n\t"
        "global_load_dwordx4 v[68:71], %[P3], off sc0 sc1\n\t"
        "s_sleep 1\n\t"                    // pace: ~1 sleep per 2 checks
        "s_branch 1b\n\t"
        "3:\n\t"                           // ---- accept A (v40..v55)
        "s_waitcnt vmcnt(0)\n\t"           // drain in-flight B round
        "v_mov_b32 %[O0], v40\n\t"  "v_mov_b32 %[O1], v41\n\t"
        "v_mov_b32 %[O2], v42\n\t"  "v_mov_b32 %[O3], v43\n\t"
        "v_mov_b32 %[O4], v44\n\t"  "v_mov_b32 %[O5], v45\n\t"
        "v_mov_b32 %[O6], v46\n\t"  "v_mov_b32 %[O7], v47\n\t"
        "v_mov_b32 %[O8], v48\n\t"  "v_mov_b32 %[O9], v49\n\t"
        "v_mov_b32 %[O10], v50\n\t" "v_mov_b32 %[O11], v51\n\t"
        "v_mov_b32 %[O12], v52\n\t" "v_mov_b32 %[O13], v53\n\t"
        "v_mov_b32 %[O14], v54\n\t" "v_mov_b32 %[O15], v55\n\t"
        "s_branch 5f\n\t"
        "4:\n\t"                           // ---- accept B (v56..v71)
        "s_waitcnt vmcnt(0)\n\t"           // drain in-flight A' round
        "v_mov_b32 %[O0], v56\n\t"  "v_mov_b32 %[O1], v57\n\t"
        "v_mov_b32 %[O2], v58\n\t"  "v_mov_b32 %[O3], v59\n\t"
        "v_mov_b32 %[O4], v60\n\t"  "v_mov_b32 %[O5], v61\n\t"
        "v_mov_b32 %[O6], v62\n\t"  "v_mov_b32 %[O7], v63\n\t"
        "v_mov_b32 %[O8], v64\n\t"  "v_mov_b32 %[O9], v65\n\t"
        "v_mov_b32 %[O10], v66\n\t" "v_mov_b32 %[O11], v67\n\t"
        "v_mov_b32 %[O12], v68\n\t" "v_mov_b32 %[O13], v69\n\t"
        "v_mov_b32 %[O14], v70\n\t" "v_mov_b32 %[O15], v71\n\t"
        "5:\n\t"
        : [O0]"=&v"(q0),  [O1]"=&v"(q1),  [O2]"=&v"(q2),  [O3]"=&v"(q3),
          [O4]"=&v"(q4),  [O5]"=&v"(q5),  [O6]"=&v"(q6),  [O7]"=&v"(q7),
          [O8]"=&v"(q8),  [O9]"=&v"(q9),  [O10]"=&v"(q10), [O11]"=&v"(q11),
          [O12]"=&v"(q12), [O13]"=&v"(q13), [O14]"=&v"(q14), [O15]"=&v"(q15)
        : [P0]"v"(p0), [P1]"v"(p1), [P2]"v"(p2), [P3]"v"(p3)
        : "memory", "vcc",
          "v40","v41","v42","v43","v44","v45","v46","v47",
          "v48","v49","v50","v51","v52","v53","v54","v55",
          "v56","v57","v58","v59","v60","v61","v62","v63",
          "v64","v65","v66","v67","v68","v69","v70","v71",
          "v72");
      // decode (exact) + LDS write in fragment-native layout
      uint4v ra  = {q0, q1, q2, q3};
      uint4v rbv = {q4, q5, q6, q7};
      uint4v rc  = {q8, q9, q10, q11};
      uint4v rd  = {q12, q13, q14, q15};
      *(uint4v*)&Ah[0 * 4 + rw][colh] = ra  ^ K4;
      *(uint4v*)&Ah[1 * 4 + rw][colh] = rbv ^ K4;
      *(uint4v*)&Ah[2 * 4 + rw][colh] = rc  ^ K4;
      *(uint4v*)&Ah[3 * 4 + rw][colh] = rd  ^ K4;
    }
    __syncthreads();   // B1: stage complete

    // ---- MFMA: z_h = A @ Wh^T (fp16 inputs, fp32 accumulate). s=0: A=0.
    f32x4 acc0 = {0.f, 0.f, 0.f, 0.f};
    f32x4 acc1 = {0.f, 0.f, 0.f, 0.f};
    if (s > 0) {
#pragma unroll
      for (int kt = 0; kt < KT; ++kt) {
        half8 a = *(const half8*)&Ah[m16][kt * 32 + qd * 8];
        acc0 = __builtin_amdgcn_mfma_f32_16x16x32_f16(a, wf[kt][0], acc0, 0, 0, 0);
        acc1 = __builtin_amdgcn_mfma_f32_16x16x32_f16(a, wf[kt][1], acc1, 0, 0, 0);
      }
    }
    // C/D layout: col = lane&15, row = (lane>>4)*4 + reg; add fp32 x-part (P)
#pragma unroll
    for (int rr = 0; rr < 4; ++rr) {
      zbuf[wave][r0 + rr][m16]      = acc0[rr] + px0[rr];
      zbuf[wave][r0 + rr][16 + m16] = acc1[rr] + px1[rr];
    }
    __syncthreads();   // B2: zbuf complete (also fences Ah reads vs next stage writes)

    // ---- gates for (gr, gj), (gr, gj+1)
    float i0 = zbuf[0][gr][gj], i1 = zbuf[0][gr][gj + 1];
    float f0g = zbuf[1][gr][gj], f1g = zbuf[1][gr][gj + 1];
    float g0 = zbuf[2][gr][gj], g1 = zbuf[2][gr][gj + 1];
    float o0 = zbuf[3][gr][gj], o1 = zbuf[3][gr][gj + 1];
    float cn0 = sigm(f0g) * c0 + sigm(i0) * tanh_fast(g0);
    float cn1 = sigm(f1g) * c1 + sigm(i1) * tanh_fast(g1);
    float hn0 = sigm(o0) * tanh_fast(cn0);
    float hn1 = sigm(o1) * tanh_fast(cn1);
    c0 = cn0; c1 = cn1;

    // ---- SINGLE encoded store: enc_out[row][s][col pair] = h2 ^ KEY
    // (agent scope -> visible past per-XCD L2; dword is never 0).
    __half2 h2;
    h2.x = __float2half(hn0);
    h2.y = __float2half(hn1);
    {
      unsigned pk = __builtin_bit_cast(unsigned, h2) ^ ENC_KEY;
      __hip_atomic_store(
          (unsigned*)(enc_out + ((size_t)(g * GM + gr) * Sv + s) * Hv + cb * 32 + gj),
          pk, __ATOMIC_RELAXED, __HIP_MEMORY_SCOPE_AGENT);
    }

    // ---- next-step P gather: issued now, completes under the next poll window
    if (s + 1 < Sv) {
      int sn = s + 1;
#pragma unroll
      for (int rr = 0; rr < 4; ++rr) {
        int tk  = enc_in[(g * GM + r0 + rr) * Sv + sn];
        px0[rr] = P[(size_t)tk * 2048 + ncol];
        px1[rr] = P[(size_t)tk * 2048 + ncol + 16];
      }
    }
  }
}

// One wg per batch row: scores = enc_out[b] @ We, softmax over S, ctx, then
// pa/pt dots tiled over T. fp32 math; enc_out is XOR-encoded fp16 -> decode.
__global__ __launch_bounds__(256)
void attn_out(const __half* __restrict__ enc_out, const float* __restrict__ Wf,
              const float* __restrict__ Wa, const float* __restrict__ ba,
              const float* __restrict__ Wt, const float* __restrict__ bt,
              float* __restrict__ out)
{
  __shared__ float We[512];
  __shared__ float sc[256];
  __shared__ float ctx[512];
  __shared__ float red[8];
  const int tid = threadIdx.x;
  const int b   = blockIdx.x;
  const int wv  = tid >> 6;
  const int ln  = tid & 63;

  We[tid] = Wf[tid];
  We[tid + 256] = Wf[tid + 256];
  __syncthreads();

  const uint4* r4 = (const uint4*)(enc_out + ((size_t)b * Sv + tid) * Hv);
  float a = 0.f;
#pragma unroll 4
  for (int k = 0; k < 64; ++k) {
    uint4 v = r4[k];
    v.x ^= ENC_KEY; v.y ^= ENC_KEY; v.z ^= ENC_KEY; v.w ^= ENC_KEY;
    float2 f0 = __half22float2(__builtin_bit_cast(__half2, v.x));
    float2 f1 = __half22float2(__builtin_bit_cast(__half2, v.y));
    float2 f2 = __half22float2(__builtin_bit_cast(__half2, v.z));
    float2 f3 = __half22float2(__builtin_bit_cast(__half2, v.w));
    const float* wp = &We[8 * k];
    a += f0.x * wp[0] + f0.y * wp[1] + f1.x * wp[2] + f1.y * wp[3]
       + f2.x * wp[4] + f2.y * wp[5] + f3.x * wp[6] + f3.y * wp[7];
  }

  float m = a;
  for (int off = 32; off; off >>= 1) m = fmaxf(m, __shfl_down(m, off));
  if (ln == 0) red[wv] = m;
  __syncthreads();
  if (tid == 0) red[4] = fmaxf(fmaxf(red[0], red[1]), fmaxf(red[2], red[3]));
  __syncthreads();
  float e = __expf(a - red[4]);
  float ssum = e;
  for (int off = 32; off; off >>= 1) ssum += __shfl_down(ssum, off);
  if (ln == 0) red[wv] = ssum;
  __syncthreads();
  if (tid == 0) red[5] = red[0] + red[1] + red[2] + red[3];
  __syncthreads();
  sc[tid] = e * (1.f / red[5]);
  __syncthreads();

  {
    float a0 = 0.f, a1 = 0.f;
    const __half2* base = (const __half2*)(enc_out + (size_t)b * Sv * Hv) + tid;
#pragma unroll 4
    for (int s2 = 0; s2 < Sv; ++s2) {
      unsigned uv = __builtin_bit_cast(unsigned, base[s2 * (Hv / 2)]) ^ ENC_KEY;
      float2 f = __half22float2(__builtin_bit_cast(__half2, uv));
      float w = sc[s2];
      a0 += w * f.x;
      a1 += w * f.y;
    }
    ctx[2 * tid] = a0;
    ctx[2 * tid + 1] = a1;
  }
  __syncthreads();

  if (tid < 88) {
    const float* wr = (tid < 8) ? (Wa + tid * Hv) : (Wt + (tid - 8) * Hv);
    float o = (tid < 8) ? ba[tid] : bt[tid - 8];
    for (int k = 0; k < Hv; ++k) o += ctx[k] * wr[k];
    if (tid < 8) {
      float* o0 = out + (size_t)b * Tv * 8;
#pragma unroll
      for (int t = 0; t < Tv; ++t) o0[t * 8 + tid] = o;
    } else {
      int n = tid - 8;
      float* o1 = out + 65536 + (size_t)b * Tv * 80;
#pragma unroll
      for (int t = 0; t < Tv; ++t) o1[t * 80 + n] = o;
    }
  }
}

extern "C" void kernel_launch(void* const* d_in, const int* in_sizes, int n_in,
                              void* d_out, int out_size, void* d_ws, size_t ws_size,
                              hipStream_t stream)
{
  (void)in_sizes; (void)n_in; (void)out_size; (void)ws_size;
  const int*   enc_in = (const int*)d_in[0];
  const float* embed  = (const float*)d_in[2];
  const float* Wi     = (const float*)d_in[3];
  const float* Wh     = (const float*)d_in[4];
  const float* be     = (const float*)d_in[5];
  const float* Wa     = (const float*)d_in[11];
  const float* ba     = (const float*)d_in[12];
  const float* Wt     = (const float*)d_in[13];
  const float* bt     = (const float*)d_in[14];
  const float* Wf     = (const float*)d_in[15];
  // d_in[1] decoder_target, [6..10] decoder weights, [16] bf: dead code

  char* ws = (char*)d_ws;
  float*  P      = (float*)ws;                       // 1000 x 2048 fp32 = 8MB
  __half* encout = (__half*)(ws + (8u << 20));       // 256x256x512 fp16 = 64MB (write-once exchange)

  // enc_out must be zero (poll sentinel) each run; encoded stores are never 0.
  hipMemsetAsync(encout, 0, 64u << 20, stream);

  build_P<<<dim3(250), dim3(256), 0, stream>>>(embed, Wi, be, P);
  lstm_enc<<<dim3(256), dim3(256), 0, stream>>>(enc_in, P, Wh, encout);
  attn_out<<<dim3(256), dim3(256), 0, stream>>>(encout, Wf, Wa, ba, Wt, bt, (float*)d_out);
}